// Round 2
// baseline (1575.744 us; speedup 1.0000x reference)
//
#include <hip/hip_runtime.h>

#define F 64

// ---------- degree / normalization ----------
__global__ void k_deg_init(float* deg, int n) {
    int i = blockIdx.x * blockDim.x + threadIdx.x;
    if (i < n) deg[i] = 1.0f;  // self-loop contribution
}

__global__ void k_deg_count(const int* __restrict__ dst, float* deg, int E) {
    int e = blockIdx.x * blockDim.x + threadIdx.x;
    if (e < E) atomicAdd(&deg[dst[e]], 1.0f);
}

__global__ void k_rsqrt(float* deg, int n) {
    int i = blockIdx.x * blockDim.x + threadIdx.x;
    if (i < n) deg[i] = 1.0f / sqrtf(deg[i]);
}

// ---------- 64x64 GEMM: out[row][f] = sum_k h[row][k] * W[k][f] ----------
// One wave per row; lane = output feature. W staged in LDS (16 KB).
// Safe to call with out == h (each wave reads its row fully into a register
// before writing, rows are wave-private). No __restrict__ on h/out for that.
__global__ __launch_bounds__(256) void k_gemm64(const float* h,
                                                const float* __restrict__ W,
                                                float* out, int n) {
    __shared__ float Ws[F * F];
    int tid = threadIdx.x;
#pragma unroll
    for (int i = 0; i < 16; ++i) Ws[tid + i * 256] = W[tid + i * 256];
    __syncthreads();
    int lane = tid & 63;
    int row = blockIdx.x * 4 + (tid >> 6);
    if (row >= n) return;
    float hv = h[(size_t)row * F + lane];
    float acc = 0.0f;
#pragma unroll
    for (int k = 0; k < F; ++k)
        acc = fmaf(__shfl(hv, k), Ws[k * F + lane], acc);
    out[(size_t)row * F + lane] = acc;
}

// ---------- edge scatter: one wave per edge, lane = feature ----------
__global__ __launch_bounds__(256) void k_scatter(const float* __restrict__ t,
                                                 const float* __restrict__ dis,
                                                 const int* __restrict__ src,
                                                 const int* __restrict__ dst,
                                                 float* agg, int E) {
    int gid = blockIdx.x * blockDim.x + threadIdx.x;
    int e = gid >> 6;
    if (e >= E) return;
    int lane = gid & 63;
    int s = src[e];
    int d = dst[e];
    float nm = dis[s] * dis[d];
    float v = t[(size_t)s * F + lane] * nm;
    atomicAdd(&agg[(size_t)d * F + lane], v);
}

// ---------- epilogue: h = relu(agg + t*dis^2 + b)  (t aliased with h) ----------
__global__ void k_bias_relu(const float* __restrict__ agg,
                            const float* __restrict__ dis,
                            const float* __restrict__ b,
                            float* h, int n) {
    int i = blockIdx.x * blockDim.x + threadIdx.x;
    if (i >= n * F) return;
    int row = i >> 6;
    int f = i & 63;
    float dv = dis[row];
    float v = agg[i] + h[i] * dv * dv + b[f];
    h[i] = fmaxf(v, 0.0f);
}

// ---------- final linear: out[row][o] = sum_k h[row][k]*Wl[k][o] + bl[o] ----------
__global__ __launch_bounds__(256) void k_final(const float* __restrict__ h,
                                               const float* __restrict__ Wl,
                                               const float* __restrict__ bl,
                                               float* __restrict__ out, int n) {
    __shared__ float Ws[F * 8];
    __shared__ float bs[8];
    int tid = threadIdx.x;
    Ws[tid] = Wl[tid];
    Ws[tid + 256] = Wl[tid + 256];
    if (tid < 8) bs[tid] = bl[tid];
    __syncthreads();
    int idx = blockIdx.x * 256 + tid;
    if (idx >= n * 8) return;
    int row = idx >> 3;
    int o = idx & 7;
    const float* hr = h + (size_t)row * F;
    float acc = bs[o];
#pragma unroll
    for (int k = 0; k < F; ++k) acc = fmaf(hr[k], Ws[k * 8 + o], acc);
    out[idx] = acc;
}

extern "C" void kernel_launch(void* const* d_in, const int* in_sizes, int n_in,
                              void* d_out, int out_size, void* d_ws, size_t ws_size,
                              hipStream_t stream) {
    const float* x  = (const float*)d_in[0];
    const int*   ei = (const int*)d_in[1];
    const float* W1 = (const float*)d_in[2];
    const float* b1 = (const float*)d_in[3];
    const float* W2 = (const float*)d_in[4];
    const float* b2 = (const float*)d_in[5];
    const float* W3 = (const float*)d_in[6];
    const float* b3 = (const float*)d_in[7];
    const float* Wl = (const float*)d_in[8];
    const float* bl = (const float*)d_in[9];
    float* out = (float*)d_out;

    int n = in_sizes[0] / F;   // 100000
    int E = in_sizes[1] / 2;   // 1600000
    const int* src = ei;       // edge_index[0]
    const int* dst = ei + E;   // edge_index[1]

    // workspace layout: dis[n] | agg[n*F] | h[n*F]   (~52 MB)
    float* dis = (float*)d_ws;
    float* agg = dis + ((n + 63) & ~63);
    float* h   = agg + (size_t)n * F;

    int nb_n  = (n + 255) / 256;
    int nb_e  = (E + 255) / 256;
    int nb_g  = (n + 3) / 4;
    int nb_nf = (n * F + 255) / 256;
    int nb_sc = (int)(((size_t)E * 64 + 255) / 256);

    // normalization
    k_deg_init<<<nb_n, 256, 0, stream>>>(dis, n);
    k_deg_count<<<nb_e, 256, 0, stream>>>(dst, dis, E);
    k_rsqrt<<<nb_n, 256, 0, stream>>>(dis, n);

    const float* Wv[3] = {W1, W2, W3};
    const float* bv[3] = {b1, b2, b3};
    const float* hin = x;
    for (int l = 0; l < 3; ++l) {
        k_gemm64<<<nb_g, 256, 0, stream>>>(hin, Wv[l], h, n);
        hipMemsetAsync(agg, 0, (size_t)n * F * sizeof(float), stream);
        k_scatter<<<nb_sc, 256, 0, stream>>>(h, dis, src, dst, agg, E);
        k_bias_relu<<<nb_nf, 256, 0, stream>>>(agg, dis, bv[l], h, n);
        hin = h;
    }
    k_final<<<(n * 8 + 255) / 256, 256, 0, stream>>>(h, Wl, bl, out, n);
}

// Round 3
// 693.660 us; speedup vs baseline: 2.2716x; 2.2716x over previous
//
#include <hip/hip_runtime.h>

#define F 64

// ============ CSR build: histogram -> scan -> fill ============

__global__ void k_count(const int* __restrict__ dst, int* count, int E) {
    int e = blockIdx.x * blockDim.x + threadIdx.x;
    if (e < E) atomicAdd(&count[dst[e]], 1);
}

// per-block sum of 256 counts
__global__ void k_reduce(const int* __restrict__ c, int* __restrict__ bsum, int n) {
    __shared__ int s[256];
    int t = threadIdx.x;
    int i = blockIdx.x * 256 + t;
    s[t] = (i < n) ? c[i] : 0;
    __syncthreads();
    for (int off = 128; off > 0; off >>= 1) {
        if (t < off) s[t] += s[t + off];
        __syncthreads();
    }
    if (t == 0) bsum[blockIdx.x] = s[0];
}

// single-block exclusive scan of block sums (nb <= 512)
__global__ void k_scan_bsum(int* bs, int nb) {
    __shared__ int s[512];
    int t = threadIdx.x;
    int v = (t < nb) ? bs[t] : 0;
    s[t] = v;
    __syncthreads();
    for (int off = 1; off < 512; off <<= 1) {
        int x = (t >= off) ? s[t - off] : 0;
        __syncthreads();
        s[t] += x;
        __syncthreads();
    }
    if (t < nb) bs[t] = s[t] - v;  // exclusive, in place
}

// per-block exclusive scan + block offset -> row_start, cursor
__global__ void k_scan_write(const int* __restrict__ c, const int* __restrict__ boff,
                             int* __restrict__ row_start, int* __restrict__ cursor, int n) {
    __shared__ int s[256];
    int t = threadIdx.x;
    int i = blockIdx.x * 256 + t;
    int v = (i < n) ? c[i] : 0;
    s[t] = v;
    __syncthreads();
    for (int off = 1; off < 256; off <<= 1) {
        int x = (t >= off) ? s[t - off] : 0;
        __syncthreads();
        s[t] += x;
        __syncthreads();
    }
    if (i < n) {
        int excl = s[t] - v + boff[blockIdx.x];
        row_start[i] = excl;
        cursor[i] = excl;
    }
}

// dis = 1/sqrt(deg), deg = in-edge count + 1 (self loop)
__global__ void k_dis(const int* __restrict__ c, float* __restrict__ dis, int n) {
    int i = blockIdx.x * blockDim.x + threadIdx.x;
    if (i < n) dis[i] = rsqrtf((float)(c[i] + 1));
}

__global__ void k_fill(const int* __restrict__ src, const int* __restrict__ dst,
                       int* cursor, int* __restrict__ csr, int E) {
    int e = blockIdx.x * blockDim.x + threadIdx.x;
    if (e < E) {
        int p = atomicAdd(&cursor[dst[e]], 1);
        csr[p] = src[e];
    }
}

// ============ fused GCN layer ============
// One wave per dst node. Math (exact reorder of reference, linearity of W):
//   out = relu( (dis[d] * (sum_e dis[src]*h[src]) + dis[d]^2 * h[d]) @ W + b )
// After fill, cursor[i] == row_start[i] + count[i], so cursor doubles as row_end.
__global__ __launch_bounds__(256) void k_layer(const float* __restrict__ hin,
                                               const float* __restrict__ W,
                                               const float* __restrict__ b,
                                               const int* __restrict__ row_start,
                                               const int* __restrict__ row_end,
                                               const int* __restrict__ csr,
                                               const float* __restrict__ dis,
                                               float* __restrict__ hout, int n) {
    __shared__ float Ws[F * F];
    int tid = threadIdx.x;
#pragma unroll
    for (int i = 0; i < 16; ++i) Ws[tid + i * 256] = W[tid + i * 256];
    __syncthreads();
    int lane = tid & 63;
    int row = blockIdx.x * 4 + (tid >> 6);
    if (row >= n) return;

    float dr = dis[row];
    size_t rb = (size_t)row << 6;
    float acc = dr * hin[rb + lane];  // self-loop term (pre-factored by dr)

    int rs = row_start[row], re = row_end[row];
    for (int base = rs; base < re; base += 64) {
        int rem = re - base;
        int m = rem < 64 ? rem : 64;
        int myi = 0;
        float myd = 0.0f;
        if (lane < m) {
            myi = csr[base + lane];
            myd = dis[myi];
        }
        int mp = (m + 3) & ~3;  // pad to 4: padded lanes have myd=0 (gather row 0, x0)
        for (int j = 0; j < mp; j += 4) {
            int s0 = __shfl(myi, j), s1 = __shfl(myi, j + 1);
            int s2 = __shfl(myi, j + 2), s3 = __shfl(myi, j + 3);
            float w0 = __shfl(myd, j), w1 = __shfl(myd, j + 1);
            float w2 = __shfl(myd, j + 2), w3 = __shfl(myd, j + 3);
            float v0 = hin[((size_t)s0 << 6) + lane];
            float v1 = hin[((size_t)s1 << 6) + lane];
            float v2 = hin[((size_t)s2 << 6) + lane];
            float v3 = hin[((size_t)s3 << 6) + lane];
            acc = fmaf(w0, v0, acc);
            acc = fmaf(w1, v1, acc);
            acc = fmaf(w2, v2, acc);
            acc = fmaf(w3, v3, acc);
        }
    }
    acc *= dr;

    // transform: y[lane] = sum_k acc_k * W[k][lane] + b[lane], then ReLU
    float y = b[lane];
#pragma unroll
    for (int k = 0; k < F; ++k) y = fmaf(__shfl(acc, k), Ws[(k << 6) + lane], y);
    hout[rb + lane] = fmaxf(y, 0.0f);
}

// ============ final 64->8 linear ============
__global__ __launch_bounds__(256) void k_final(const float* __restrict__ h,
                                               const float* __restrict__ Wl,
                                               const float* __restrict__ bl,
                                               float* __restrict__ out, int n) {
    __shared__ float Ws[F * 8];
    __shared__ float bs[8];
    int tid = threadIdx.x;
    Ws[tid] = Wl[tid];
    Ws[tid + 256] = Wl[tid + 256];
    if (tid < 8) bs[tid] = bl[tid];
    __syncthreads();
    int idx = blockIdx.x * 256 + tid;
    if (idx >= n * 8) return;
    int row = idx >> 3;
    int o = idx & 7;
    const float* hr = h + (size_t)row * F;
    float acc = bs[o];
#pragma unroll
    for (int k = 0; k < F; ++k) acc = fmaf(hr[k], Ws[k * 8 + o], acc);
    out[idx] = acc;
}

extern "C" void kernel_launch(void* const* d_in, const int* in_sizes, int n_in,
                              void* d_out, int out_size, void* d_ws, size_t ws_size,
                              hipStream_t stream) {
    const float* x  = (const float*)d_in[0];
    const int*   ei = (const int*)d_in[1];
    const float* W1 = (const float*)d_in[2];
    const float* b1 = (const float*)d_in[3];
    const float* W2 = (const float*)d_in[4];
    const float* b2 = (const float*)d_in[5];
    const float* W3 = (const float*)d_in[6];
    const float* b3 = (const float*)d_in[7];
    const float* Wl = (const float*)d_in[8];
    const float* bl = (const float*)d_in[9];
    float* out = (float*)d_out;

    int n = in_sizes[0] / F;   // 100000
    int E = in_sizes[1] / 2;   // 1600000
    const int* src = ei;
    const int* dst = ei + E;

    int np = (n + 255) & ~255;  // padded n
    int nb = (n + 255) / 256;   // blocks over nodes (<=512 for scan)

    // workspace layout (ints/floats are 4B): ~59 MB total
    int*   count     = (int*)d_ws;
    int*   row_start = count + np;
    int*   cursor    = row_start + np;
    int*   bsum      = cursor + np;          // nb entries (pad 512)
    float* dis       = (float*)(bsum + 512);
    int*   csr       = (int*)(dis + np);
    float* A         = (float*)(csr + ((E + 255) & ~255));
    float* B         = A + (size_t)n * F;

    int nb_e = (E + 255) / 256;

    // ---- CSR build + norm ----
    hipMemsetAsync(count, 0, (size_t)np * sizeof(int), stream);
    k_count<<<nb_e, 256, 0, stream>>>(dst, count, E);
    k_reduce<<<nb, 256, 0, stream>>>(count, bsum, n);
    k_scan_bsum<<<1, 512, 0, stream>>>(bsum, nb);
    k_scan_write<<<nb, 256, 0, stream>>>(count, bsum, row_start, cursor, n);
    k_dis<<<nb, 256, 0, stream>>>(count, dis, n);
    k_fill<<<nb_e, 256, 0, stream>>>(src, dst, cursor, csr, E);
    // after k_fill: cursor[i] == row_start[i] + count[i] == row_end[i]

    // ---- 3 fused layers, ping-pong A/B ----
    int nb_l = (n + 3) / 4;
    k_layer<<<nb_l, 256, 0, stream>>>(x, W1, b1, row_start, cursor, csr, dis, A, n);
    k_layer<<<nb_l, 256, 0, stream>>>(A, W2, b2, row_start, cursor, csr, dis, B, n);
    k_layer<<<nb_l, 256, 0, stream>>>(B, W3, b3, row_start, cursor, csr, dis, A, n);

    // ---- final linear ----
    k_final<<<(n * 8 + 255) / 256, 256, 0, stream>>>(A, Wl, bl, out, n);
}

// Round 4
// 494.577 us; speedup vs baseline: 3.1860x; 1.4025x over previous
//
#include <hip/hip_runtime.h>

#define F 64

__device__ __forceinline__ float rlane(float v, int l) {
    return __uint_as_float(__builtin_amdgcn_readlane(__float_as_uint(v), l));
}

// ============ CSR build (rows padded to multiple of 16 edges) ============

__global__ void k_count(const int* __restrict__ dst, int* count, int E) {
    int e = blockIdx.x * blockDim.x + threadIdx.x;
    if (e < E) atomicAdd(&count[dst[e]], 1);
}

// pc = padded count (multiple of 16), dis = 1/sqrt(deg+1)
__global__ void k_pc_dis(const int* __restrict__ count, int* __restrict__ pc,
                         float* __restrict__ dis, int n, int np) {
    int i = blockIdx.x * blockDim.x + threadIdx.x;
    if (i >= np) return;
    if (i < n) {
        int c = count[i];
        pc[i] = (c + 15) & ~15;
        dis[i] = rsqrtf((float)(c + 1));
    } else {
        pc[i] = 0;
    }
}

__global__ void k_reduce(const int* __restrict__ c, int* __restrict__ bsum, int n) {
    __shared__ int s[256];
    int t = threadIdx.x;
    int i = blockIdx.x * 256 + t;
    s[t] = (i < n) ? c[i] : 0;
    __syncthreads();
    for (int off = 128; off > 0; off >>= 1) {
        if (t < off) s[t] += s[t + off];
        __syncthreads();
    }
    if (t == 0) bsum[blockIdx.x] = s[0];
}

__global__ void k_scan_bsum(int* bs, int nb) {
    __shared__ int s[512];
    int t = threadIdx.x;
    int v = (t < nb) ? bs[t] : 0;
    s[t] = v;
    __syncthreads();
    for (int off = 1; off < 512; off <<= 1) {
        int x = (t >= off) ? s[t - off] : 0;
        __syncthreads();
        s[t] += x;
        __syncthreads();
    }
    if (t < nb) bs[t] = s[t] - v;  // exclusive
}

// exclusive scan of pc -> row_start (i <= n gets the total at i==n), cursor
__global__ void k_scan_write(const int* __restrict__ pc, const int* __restrict__ boff,
                             int* __restrict__ row_start, int* __restrict__ cursor, int n) {
    __shared__ int s[256];
    int t = threadIdx.x;
    int i = blockIdx.x * 256 + t;
    int v = (i < n) ? pc[i] : 0;
    s[t] = v;
    __syncthreads();
    for (int off = 1; off < 256; off <<= 1) {
        int x = (t >= off) ? s[t - off] : 0;
        __syncthreads();
        s[t] += x;
        __syncthreads();
    }
    if (i <= n) {
        int excl = s[t] - v + boff[blockIdx.x];
        row_start[i] = excl;
        cursor[i] = excl;
    }
}

// pad slots must point at the zero row n
__global__ void k_csr_init(int* __restrict__ csr, int n, int cap) {
    int i = blockIdx.x * blockDim.x + threadIdx.x;
    if (i < cap) csr[i] = n;
}

__global__ void k_fill(const int* __restrict__ src, const int* __restrict__ dst,
                       int* cursor, int* __restrict__ csr, int E) {
    int e = blockIdx.x * blockDim.x + threadIdx.x;
    if (e < E) {
        int p = atomicAdd(&cursor[dst[e]], 1);
        csr[p] = src[e];
    }
}

// hs0 = dis * x, with zero row at index n
__global__ void k_prep(const float* __restrict__ x, const float* __restrict__ dis,
                       float* __restrict__ hs, int n) {
    int i = blockIdx.x * blockDim.x + threadIdx.x;
    int tot = (n + 1) * F;
    if (i >= tot) return;
    int row = i >> 6;
    hs[i] = (row < n) ? dis[row] * x[i] : 0.0f;
}

__global__ void k_zrow(float* __restrict__ hs, int n) {
    hs[(size_t)n * F + threadIdx.x] = 0.0f;
}

// ============ fused GCN layer: 4 rows per wave, DS-free gather ============
// out_r = relu( (dis_r * (hs[r] + sum_{s in N(r)} hs[s])) @ W + b )
// hout_r = scale_out ? dis_r * out_r : out_r
// Requires n % 4 == 0 (n = 100000). Pad CSR slots index the zero row n.
__global__ __launch_bounds__(256) void k_layer(const float* __restrict__ hin,
                                               const float* __restrict__ W,
                                               const float* __restrict__ b,
                                               const int* __restrict__ row_start,
                                               const int* __restrict__ csr,
                                               const float* __restrict__ dis,
                                               float* __restrict__ hout,
                                               int n, int scale_out) {
    __shared__ float Ws[F * F];
    int tid = threadIdx.x;
#pragma unroll
    for (int i = 0; i < 16; ++i) Ws[tid + i * 256] = W[tid + i * 256];
    __syncthreads();
    int lane = tid & 63;
    int r0 = (blockIdx.x * 4 + (tid >> 6)) * 4;
    if (r0 >= n) return;

    // self terms (hs already carries dis factor)
    float acc0 = hin[((size_t)(r0 + 0) << 6) + lane];
    float acc1 = hin[((size_t)(r0 + 1) << 6) + lane];
    float acc2 = hin[((size_t)(r0 + 2) << 6) + lane];
    float acc3 = hin[((size_t)(r0 + 3) << 6) + lane];

    int s0 = row_start[r0];
    int s1 = row_start[r0 + 1];
    int s2 = row_start[r0 + 2];
    int s3 = row_start[r0 + 3];
    int s4 = row_start[r0 + 4];

    const int4* p4 = (const int4*)csr;
    for (int j = s0; j < s4; j += 16) {      // each 16-batch is row-pure (pad-16)
        int g = j >> 2;
        int4 qa = p4[g], qb = p4[g + 1], qc = p4[g + 2], qd = p4[g + 3];
        float v0 = hin[((size_t)qa.x << 6) + lane];
        float v1 = hin[((size_t)qa.y << 6) + lane];
        float v2 = hin[((size_t)qa.z << 6) + lane];
        float v3 = hin[((size_t)qa.w << 6) + lane];
        float v4 = hin[((size_t)qb.x << 6) + lane];
        float v5 = hin[((size_t)qb.y << 6) + lane];
        float v6 = hin[((size_t)qb.z << 6) + lane];
        float v7 = hin[((size_t)qb.w << 6) + lane];
        float v8 = hin[((size_t)qc.x << 6) + lane];
        float v9 = hin[((size_t)qc.y << 6) + lane];
        float va = hin[((size_t)qc.z << 6) + lane];
        float vb = hin[((size_t)qc.w << 6) + lane];
        float vc = hin[((size_t)qd.x << 6) + lane];
        float vd = hin[((size_t)qd.y << 6) + lane];
        float ve = hin[((size_t)qd.z << 6) + lane];
        float vf = hin[((size_t)qd.w << 6) + lane];
        float t = (((v0 + v1) + (v2 + v3)) + ((v4 + v5) + (v6 + v7))) +
                  (((v8 + v9) + (va + vb)) + ((vc + vd) + (ve + vf)));
        if (j >= s3)      acc3 += t;
        else if (j >= s2) acc2 += t;
        else if (j >= s1) acc1 += t;
        else              acc0 += t;
    }

    acc0 *= dis[r0 + 0];
    acc1 *= dis[r0 + 1];
    acc2 *= dis[r0 + 2];
    acc3 *= dis[r0 + 3];

    float bb = b[lane];
    float y0 = bb, y1 = bb, y2 = bb, y3 = bb;
#pragma unroll
    for (int k = 0; k < F; ++k) {
        float w = Ws[(k << 6) + lane];
        y0 = fmaf(rlane(acc0, k), w, y0);
        y1 = fmaf(rlane(acc1, k), w, y1);
        y2 = fmaf(rlane(acc2, k), w, y2);
        y3 = fmaf(rlane(acc3, k), w, y3);
    }
    y0 = fmaxf(y0, 0.0f);
    y1 = fmaxf(y1, 0.0f);
    y2 = fmaxf(y2, 0.0f);
    y3 = fmaxf(y3, 0.0f);
    if (scale_out) {
        y0 *= dis[r0 + 0];
        y1 *= dis[r0 + 1];
        y2 *= dis[r0 + 2];
        y3 *= dis[r0 + 3];
    }
    hout[((size_t)(r0 + 0) << 6) + lane] = y0;
    hout[((size_t)(r0 + 1) << 6) + lane] = y1;
    hout[((size_t)(r0 + 2) << 6) + lane] = y2;
    hout[((size_t)(r0 + 3) << 6) + lane] = y3;
}

// ============ final 64->8 linear ============
__global__ __launch_bounds__(256) void k_final(const float* __restrict__ h,
                                               const float* __restrict__ Wl,
                                               const float* __restrict__ bl,
                                               float* __restrict__ out, int n) {
    __shared__ float Ws[F * 8];
    __shared__ float bs[8];
    int tid = threadIdx.x;
    Ws[tid] = Wl[tid];
    Ws[tid + 256] = Wl[tid + 256];
    if (tid < 8) bs[tid] = bl[tid];
    __syncthreads();
    int idx = blockIdx.x * 256 + tid;
    if (idx >= n * 8) return;
    int row = idx >> 3;
    int o = idx & 7;
    const float* hr = h + (size_t)row * F;
    float acc = bs[o];
#pragma unroll
    for (int k = 0; k < F; ++k) acc = fmaf(hr[k], Ws[k * 8 + o], acc);
    out[idx] = acc;
}

extern "C" void kernel_launch(void* const* d_in, const int* in_sizes, int n_in,
                              void* d_out, int out_size, void* d_ws, size_t ws_size,
                              hipStream_t stream) {
    const float* x  = (const float*)d_in[0];
    const int*   ei = (const int*)d_in[1];
    const float* W1 = (const float*)d_in[2];
    const float* b1 = (const float*)d_in[3];
    const float* W2 = (const float*)d_in[4];
    const float* b2 = (const float*)d_in[5];
    const float* W3 = (const float*)d_in[6];
    const float* b3 = (const float*)d_in[7];
    const float* Wl = (const float*)d_in[8];
    const float* bl = (const float*)d_in[9];
    float* out = (float*)d_out;

    int n = in_sizes[0] / F;   // 100000 (n % 4 == 0)
    int E = in_sizes[1] / 2;   // 1600000
    const int* src = ei;
    const int* dst = ei + E;

    int np = (n + 256) & ~255;            // >= n+1, multiple of 256
    int nb = (np + 255) / 256;            // blocks over nodes (<=512 for scan)
    int cap = E + 15 * n + 64;            // worst-case padded CSR size

    // workspace layout (all 4B elements, segments 16B aligned): ~66 MB
    int*   count     = (int*)d_ws;
    int*   pc        = count + np;
    int*   row_start = pc + np;
    int*   cursor    = row_start + np;
    int*   bsum      = cursor + np;       // 512
    float* dis       = (float*)(bsum + 512);
    int*   csr       = (int*)(dis + np);
    float* buf1      = (float*)(csr + ((cap + 3) & ~3));
    float* buf2      = buf1 + (size_t)(n + 1) * F;

    int nb_e = (E + 255) / 256;

    // ---- CSR build (padded) + norm ----
    hipMemsetAsync(count, 0, (size_t)np * sizeof(int), stream);
    k_count<<<nb_e, 256, 0, stream>>>(dst, count, E);
    k_pc_dis<<<nb, 256, 0, stream>>>(count, pc, dis, n, np);
    k_reduce<<<nb, 256, 0, stream>>>(pc, bsum, n);
    k_scan_bsum<<<1, 512, 0, stream>>>(bsum, nb);
    k_scan_write<<<nb, 256, 0, stream>>>(pc, bsum, row_start, cursor, n);
    k_csr_init<<<(cap + 255) / 256, 256, 0, stream>>>(csr, n, cap);
    k_fill<<<nb_e, 256, 0, stream>>>(src, dst, cursor, csr, E);

    // ---- hs0 = dis*x (row n zeroed) ----
    k_prep<<<((n + 1) * F + 255) / 256, 256, 0, stream>>>(x, dis, buf1, n);

    // ---- 3 fused layers, ping-pong ----
    int nb_l = (n / 4 + 3) / 4;   // 4 rows/wave, 4 waves/block
    k_layer<<<nb_l, 256, 0, stream>>>(buf1, W1, b1, row_start, csr, dis, buf2, n, 1);
    k_zrow<<<1, 64, 0, stream>>>(buf2, n);   // buf1 row n stays zero from k_prep
    k_layer<<<nb_l, 256, 0, stream>>>(buf2, W2, b2, row_start, csr, dis, buf1, n, 1);
    k_layer<<<nb_l, 256, 0, stream>>>(buf1, W3, b3, row_start, csr, dis, buf2, n, 0);

    // ---- final linear ----
    k_final<<<(n * 8 + 255) / 256, 256, 0, stream>>>(buf2, Wl, bl, out, n);
}